// Round 1
// baseline (4361.146 us; speedup 1.0000x reference)
//
#include <hip/hip_runtime.h>
#include <math.h>

#define NN 100000
#define D_IN 128
#define D_H1 128
#define D_H2 64
#define D_O 10

// ---- workspace layout (bytes) ----
// dis:  [0, 400KB)
// g1:   [1MB, 1MB+51.2MB)            (reused later: g2 at same offset)
// acc2: [57MB+... ) -- see below
static const size_t OFF_DIS  = 0;
static const size_t OFF_G1   = (size_t)1 << 20;                    // N*128 f32 = 51.2MB
static const size_t OFF_ACC1 = OFF_G1 + ((size_t)56 << 20);        // N*128 f32 (becomes h1)
static const size_t OFF_G2   = OFF_G1;                             // N*64 f32 (g1 dead by then)
static const size_t OFF_ACC2 = OFF_G1 + ((size_t)28 << 20);        // N*64 f32 (becomes h2)
// NOTE: acc2 overlaps the tail of g1's region -> acc2 is memset AFTER finish1.

__global__ __launch_bounds__(256) void count_deg_kernel(
    const int* __restrict__ dst, float* __restrict__ deg, int E) {
  int i = blockIdx.x * 256 + threadIdx.x;
  if (i < E) atomicAdd(&deg[dst[i]], 1.0f);
}

__global__ __launch_bounds__(256) void make_dis_kernel(float* __restrict__ deg, int n) {
  int i = blockIdx.x * 256 + threadIdx.x;
  if (i < n) deg[i] = rsqrtf(deg[i] + 1.0f);  // +1 = self-loop; always > 0
}

// C[row, :] = scale(row) * (A[row,:] @ W)   A: [nrows, K], W: [K, NOUT]
// block: 256 threads, 64 rows/block, micro-tile 4 rows x TN cols per thread.
template <int K, int NOUT, int TN>
__global__ __launch_bounds__(256) void gemm_scale_kernel(
    const float* __restrict__ A, const float* __restrict__ W,
    const float* __restrict__ dis, float* __restrict__ out, int nrows) {
  constexpr int BK = 32;
  __shared__ float ws[BK * NOUT];
  __shared__ float xs[64 * 33];  // +1 pad breaks 4-way bank conflict on row reads
  const int tid = threadIdx.x;
  const int rg = tid >> 4;   // 0..15 row-group
  const int cg = tid & 15;   // 0..15 col-group
  const int row0 = blockIdx.x * 64;

  float acc[4][TN];
#pragma unroll
  for (int r = 0; r < 4; ++r)
#pragma unroll
    for (int j = 0; j < TN; ++j) acc[r][j] = 0.f;

  for (int k0 = 0; k0 < K; k0 += BK) {
    __syncthreads();
    // stage W chunk (BK x NOUT), contiguous float4 copy
    for (int i = tid * 4; i < BK * NOUT; i += 256 * 4) {
      *(float4*)(ws + i) = *(const float4*)(W + (size_t)k0 * NOUT + i);
    }
    // stage x chunk (64 rows x BK), coalesced global float4, padded LDS rows
    for (int l = tid * 4; l < 64 * BK; l += 256 * 4) {
      int rr = l >> 5;
      int kk = l & 31;
      int row = row0 + rr;
      float4 v;
      if (row < nrows) v = *(const float4*)(A + (size_t)row * K + k0 + kk);
      else v = make_float4(0.f, 0.f, 0.f, 0.f);
      float* p = xs + rr * 33 + kk;
      p[0] = v.x; p[1] = v.y; p[2] = v.z; p[3] = v.w;
    }
    __syncthreads();
#pragma unroll
    for (int kk = 0; kk < BK; ++kk) {
      float xv[4];
#pragma unroll
      for (int r = 0; r < 4; ++r) xv[r] = xs[(rg * 4 + r) * 33 + kk];
      const float* wr = ws + kk * NOUT + cg * TN;
#pragma unroll
      for (int j4 = 0; j4 < TN; j4 += 4) {
        float4 wv = *(const float4*)(wr + j4);
#pragma unroll
        for (int r = 0; r < 4; ++r) {
          acc[r][j4 + 0] += xv[r] * wv.x;
          acc[r][j4 + 1] += xv[r] * wv.y;
          acc[r][j4 + 2] += xv[r] * wv.z;
          acc[r][j4 + 3] += xv[r] * wv.w;
        }
      }
    }
  }
#pragma unroll
  for (int r = 0; r < 4; ++r) {
    int row = row0 + rg * 4 + r;
    if (row < nrows) {
      float s = dis ? dis[row] : 1.0f;
#pragma unroll
      for (int j4 = 0; j4 < TN; j4 += 4) {
        float4 o;
        o.x = s * acc[r][j4 + 0];
        o.y = s * acc[r][j4 + 1];
        o.z = s * acc[r][j4 + 2];
        o.w = s * acc[r][j4 + 3];
        *(float4*)(out + (size_t)row * NOUT + cg * TN + j4) = o;
      }
    }
  }
}

// acc[dst] += g[src] over edges; one thread per (edge, 4-feature chunk)
template <int F>
__global__ __launch_bounds__(256) void scatter_kernel(
    const float* __restrict__ g, const int* __restrict__ src,
    const int* __restrict__ dst, float* __restrict__ acc, int E) {
  constexpr int CH = F / 4;
  int idx = blockIdx.x * 256 + threadIdx.x;
  if (idx >= E * CH) return;
  int e = idx / CH;
  int c = (idx & (CH - 1)) * 4;
  int s = src[e], d = dst[e];
  float4 v = *(const float4*)(g + (size_t)s * F + c);
  float* p = acc + (size_t)d * F + c;
  atomicAdd(p + 0, v.x);
  atomicAdd(p + 1, v.y);
  atomicAdd(p + 2, v.z);
  atomicAdd(p + 3, v.w);
}

// h = relu(dis[v]*(acc + g) + b[c]), written in-place into acc
template <int F>
__global__ __launch_bounds__(256) void finish_kernel(
    const float* __restrict__ g, float* __restrict__ acc,
    const float* __restrict__ dis, const float* __restrict__ b, int n) {
  int idx = blockIdx.x * 256 + threadIdx.x;
  if (idx >= n * F) return;
  int v = idx / F;
  int c = idx & (F - 1);
  float r = dis[v] * (acc[idx] + g[idx]) + b[c];
  acc[idx] = r > 0.f ? r : 0.f;
}

// logits = h @ Wf + bf, softmax -> out. One thread per row.
__global__ __launch_bounds__(256) void final_kernel(
    const float* __restrict__ h, const float* __restrict__ Wf,
    const float* __restrict__ bf, float* __restrict__ out, int n) {
  __shared__ float wfs[D_H2 * D_O];
  __shared__ float bfs[D_O];
  int tid = threadIdx.x;
  for (int i = tid; i < D_H2 * D_O; i += 256) wfs[i] = Wf[i];
  if (tid < D_O) bfs[tid] = bf[tid];
  __syncthreads();
  int row = blockIdx.x * 256 + tid;
  if (row >= n) return;
  float acc[D_O];
#pragma unroll
  for (int j = 0; j < D_O; ++j) acc[j] = bfs[j];
  const float* hp = h + (size_t)row * D_H2;
  for (int k = 0; k < D_H2; k += 4) {
    float4 hv = *(const float4*)(hp + k);
    const float* w = wfs + k * D_O;
#pragma unroll
    for (int j = 0; j < D_O; ++j) acc[j] += hv.x * w[j];
    w += D_O;
#pragma unroll
    for (int j = 0; j < D_O; ++j) acc[j] += hv.y * w[j];
    w += D_O;
#pragma unroll
    for (int j = 0; j < D_O; ++j) acc[j] += hv.z * w[j];
    w += D_O;
#pragma unroll
    for (int j = 0; j < D_O; ++j) acc[j] += hv.w * w[j];
  }
  float m = acc[0];
#pragma unroll
  for (int j = 1; j < D_O; ++j) m = fmaxf(m, acc[j]);
  float s = 0.f;
#pragma unroll
  for (int j = 0; j < D_O; ++j) {
    acc[j] = expf(acc[j] - m);
    s += acc[j];
  }
  float inv = 1.0f / s;
  float* op = out + (size_t)row * D_O;
#pragma unroll
  for (int j = 0; j < D_O; ++j) op[j] = acc[j] * inv;
}

extern "C" void kernel_launch(void* const* d_in, const int* in_sizes, int n_in,
                              void* d_out, int out_size, void* d_ws, size_t ws_size,
                              hipStream_t stream) {
  const float* x  = (const float*)d_in[0];
  const int*   ei = (const int*)d_in[1];
  const float* W1 = (const float*)d_in[2];
  const float* b1 = (const float*)d_in[3];
  const float* W2 = (const float*)d_in[4];
  const float* b2 = (const float*)d_in[5];
  const float* Wf = (const float*)d_in[6];
  const float* bf = (const float*)d_in[7];
  float* out = (float*)d_out;

  const int E = in_sizes[1] / 2;
  const int* src = ei;
  const int* dst = ei + E;

  char* ws = (char*)d_ws;
  float* dis  = (float*)(ws + OFF_DIS);
  float* g1   = (float*)(ws + OFF_G1);
  float* acc1 = (float*)(ws + OFF_ACC1);  // becomes h1
  float* g2   = (float*)(ws + OFF_G2);
  float* acc2 = (float*)(ws + OFF_ACC2);  // becomes h2

  // ---- degree / normalization ----
  hipMemsetAsync(dis, 0, (size_t)NN * 4, stream);
  hipMemsetAsync(acc1, 0, (size_t)NN * D_H1 * 4, stream);
  count_deg_kernel<<<(E + 255) / 256, 256, 0, stream>>>(dst, dis, E);
  make_dis_kernel<<<(NN + 255) / 256, 256, 0, stream>>>(dis, NN);

  // ---- layer 1 ----
  gemm_scale_kernel<D_IN, D_H1, 8>
      <<<(NN + 63) / 64, 256, 0, stream>>>(x, W1, dis, g1, NN);
  scatter_kernel<D_H1>
      <<<((size_t)E * (D_H1 / 4) + 255) / 256, 256, 0, stream>>>(g1, src, dst, acc1, E);
  finish_kernel<D_H1>
      <<<((size_t)NN * D_H1 + 255) / 256, 256, 0, stream>>>(g1, acc1, dis, b1, NN);

  // ---- layer 2 (acc2 region overlaps dead g1 -> zero it only now) ----
  hipMemsetAsync(acc2, 0, (size_t)NN * D_H2 * 4, stream);
  gemm_scale_kernel<D_H1, D_H2, 4>
      <<<(NN + 63) / 64, 256, 0, stream>>>(acc1, W2, dis, g2, NN);
  scatter_kernel<D_H2>
      <<<((size_t)E * (D_H2 / 4) + 255) / 256, 256, 0, stream>>>(g2, src, dst, acc2, E);
  finish_kernel<D_H2>
      <<<((size_t)NN * D_H2 + 255) / 256, 256, 0, stream>>>(g2, acc2, dis, b2, NN);

  // ---- head + softmax ----
  final_kernel<<<(NN + 255) / 256, 256, 0, stream>>>(acc2, Wf, bf, out, NN);
}

// Round 2
// 736.315 us; speedup vs baseline: 5.9229x; 5.9229x over previous
//
#include <hip/hip_runtime.h>
#include <math.h>

#define NN 100000
#define D_IN 128
#define D_H1 128
#define D_H2 64
#define D_O 10

// ---- workspace layout (bytes), total ~110.7 MB (prior round used 111 MB OK) ----
static const size_t OFF_G1     = 0;                 // N*128 f32 = 51.2 MB (later: g2 [25.6MB] + h2 [25.6MB])
static const size_t OFF_H1     = 51200000;          // N*128 f32 = 51.2 MB
static const size_t OFF_COL    = 102400000;         // E int32   =  6.4 MB
static const size_t OFF_DIS    = 108800000;         // N f32
static const size_t OFF_ROWPTR = 109300000;         // (N+1) int32
static const size_t OFF_CURSOR = 109800000;         // N int32
static const size_t OFF_DEGI   = 110300000;         // N int32
// g2 = OFF_G1 (g1 dead after gather1); h2 = OFF_G1 + 25.6MB

__global__ __launch_bounds__(256) void count_deg_kernel(
    const int* __restrict__ dst, int* __restrict__ deg, int E) {
  int i = blockIdx.x * 256 + threadIdx.x;
  if (i < E) atomicAdd(&deg[dst[i]], 1);
}

__global__ __launch_bounds__(256) void make_dis_kernel(
    const int* __restrict__ deg, float* __restrict__ dis, int n) {
  int i = blockIdx.x * 256 + threadIdx.x;
  if (i < n) dis[i] = rsqrtf((float)deg[i] + 1.0f);  // +1 = self-loop
}

// single-block exclusive scan of deg[0..n) -> row_ptr[0..n], cursor copy
__global__ __launch_bounds__(1024) void scan_kernel(
    const int* __restrict__ deg, int* __restrict__ row_ptr,
    int* __restrict__ cursor, int n) {
  __shared__ int sm[1024];
  __shared__ int carry_s;
  const int tid = threadIdx.x;
  if (tid == 0) carry_s = 0;
  __syncthreads();
  for (int base = 0; base < n; base += 1024) {
    int i = base + tid;
    int v = (i < n) ? deg[i] : 0;
    sm[tid] = v;
    __syncthreads();
#pragma unroll
    for (int off = 1; off < 1024; off <<= 1) {
      int t = (tid >= off) ? sm[tid - off] : 0;
      __syncthreads();
      sm[tid] += t;
      __syncthreads();
    }
    int incl = sm[tid];
    int carry = carry_s;
    if (i < n) {
      int ex = carry + incl - v;
      row_ptr[i] = ex;
      cursor[i] = ex;
    }
    __syncthreads();
    if (tid == 1023) carry_s = carry + incl;
    __syncthreads();
  }
  if (tid == 0) row_ptr[n] = carry_s;
}

__global__ __launch_bounds__(256) void fill_csr_kernel(
    const int* __restrict__ src, const int* __restrict__ dst,
    int* __restrict__ cursor, int* __restrict__ col, int E) {
  int e = blockIdx.x * 256 + threadIdx.x;
  if (e < E) {
    int p = atomicAdd(&cursor[dst[e]], 1);
    col[p] = src[e];
  }
}

// C[row, :] = dis(row) * (A[row,:] @ W)   A: [nrows, K], W: [K, NOUT]
template <int K, int NOUT, int TN>
__global__ __launch_bounds__(256) void gemm_scale_kernel(
    const float* __restrict__ A, const float* __restrict__ W,
    const float* __restrict__ dis, float* __restrict__ out, int nrows) {
  constexpr int BK = 32;
  __shared__ float ws[BK * NOUT];
  __shared__ float xs[64 * 33];
  const int tid = threadIdx.x;
  const int rg = tid >> 4;
  const int cg = tid & 15;
  const int row0 = blockIdx.x * 64;

  float acc[4][TN];
#pragma unroll
  for (int r = 0; r < 4; ++r)
#pragma unroll
    for (int j = 0; j < TN; ++j) acc[r][j] = 0.f;

  for (int k0 = 0; k0 < K; k0 += BK) {
    __syncthreads();
    for (int i = tid * 4; i < BK * NOUT; i += 256 * 4) {
      *(float4*)(ws + i) = *(const float4*)(W + (size_t)k0 * NOUT + i);
    }
    for (int l = tid * 4; l < 64 * BK; l += 256 * 4) {
      int rr = l >> 5;
      int kk = l & 31;
      int row = row0 + rr;
      float4 v;
      if (row < nrows) v = *(const float4*)(A + (size_t)row * K + k0 + kk);
      else v = make_float4(0.f, 0.f, 0.f, 0.f);
      float* p = xs + rr * 33 + kk;
      p[0] = v.x; p[1] = v.y; p[2] = v.z; p[3] = v.w;
    }
    __syncthreads();
#pragma unroll
    for (int kk = 0; kk < BK; ++kk) {
      float xv[4];
#pragma unroll
      for (int r = 0; r < 4; ++r) xv[r] = xs[(rg * 4 + r) * 33 + kk];
      const float* wr = ws + kk * NOUT + cg * TN;
#pragma unroll
      for (int j4 = 0; j4 < TN; j4 += 4) {
        float4 wv = *(const float4*)(wr + j4);
#pragma unroll
        for (int r = 0; r < 4; ++r) {
          acc[r][j4 + 0] += xv[r] * wv.x;
          acc[r][j4 + 1] += xv[r] * wv.y;
          acc[r][j4 + 2] += xv[r] * wv.z;
          acc[r][j4 + 3] += xv[r] * wv.w;
        }
      }
    }
  }
#pragma unroll
  for (int r = 0; r < 4; ++r) {
    int row = row0 + rg * 4 + r;
    if (row < nrows) {
      float s = dis[row];
#pragma unroll
      for (int j4 = 0; j4 < TN; j4 += 4) {
        float4 o;
        o.x = s * acc[r][j4 + 0];
        o.y = s * acc[r][j4 + 1];
        o.z = s * acc[r][j4 + 2];
        o.w = s * acc[r][j4 + 3];
        *(float4*)(out + (size_t)row * NOUT + cg * TN + j4) = o;
      }
    }
  }
}

// h[v,:] = relu(dis[v]*(sum_{s in col[row_ptr[v]..row_ptr[v+1])} g[s,:] + g[v,:]) + b)
// LOG_LPN lanes-per-node = F/4 chunk ownership (32 lanes for F=128, 16 for F=64)
template <int F, int LOG_LPN>
__global__ __launch_bounds__(256) void gather_kernel(
    const float* __restrict__ g, const int* __restrict__ col,
    const int* __restrict__ row_ptr, const float* __restrict__ dis,
    const float* __restrict__ b, float* __restrict__ h, int n) {
  constexpr int LPN = 1 << LOG_LPN;
  int gid = blockIdx.x * 256 + threadIdx.x;
  int v = gid >> LOG_LPN;
  if (v >= n) return;
  int c = (gid & (LPN - 1)) * 4;
  int start = row_ptr[v];
  int end = row_ptr[v + 1];
  float4 acc = *(const float4*)(g + (size_t)v * F + c);  // self-loop
  int s_next = (start < end) ? col[start] : 0;
  for (int e = start; e < end; ++e) {
    int s = s_next;
    if (e + 1 < end) s_next = col[e + 1];
    float4 t = *(const float4*)(g + (size_t)s * F + c);
    acc.x += t.x; acc.y += t.y; acc.z += t.z; acc.w += t.w;
  }
  float dv = dis[v];
  float4 bv = *(const float4*)(b + c);
  float4 r;
  r.x = fmaxf(dv * acc.x + bv.x, 0.f);
  r.y = fmaxf(dv * acc.y + bv.y, 0.f);
  r.z = fmaxf(dv * acc.z + bv.z, 0.f);
  r.w = fmaxf(dv * acc.w + bv.w, 0.f);
  *(float4*)(h + (size_t)v * F + c) = r;
}

// logits = h @ Wf + bf, softmax -> out. One thread per row.
__global__ __launch_bounds__(256) void final_kernel(
    const float* __restrict__ h, const float* __restrict__ Wf,
    const float* __restrict__ bf, float* __restrict__ out, int n) {
  __shared__ float wfs[D_H2 * D_O];
  __shared__ float bfs[D_O];
  int tid = threadIdx.x;
  for (int i = tid; i < D_H2 * D_O; i += 256) wfs[i] = Wf[i];
  if (tid < D_O) bfs[tid] = bf[tid];
  __syncthreads();
  int row = blockIdx.x * 256 + tid;
  if (row >= n) return;
  float acc[D_O];
#pragma unroll
  for (int j = 0; j < D_O; ++j) acc[j] = bfs[j];
  const float* hp = h + (size_t)row * D_H2;
  for (int k = 0; k < D_H2; k += 4) {
    float4 hv = *(const float4*)(hp + k);
    const float* w = wfs + k * D_O;
#pragma unroll
    for (int j = 0; j < D_O; ++j) acc[j] += hv.x * w[j];
    w += D_O;
#pragma unroll
    for (int j = 0; j < D_O; ++j) acc[j] += hv.y * w[j];
    w += D_O;
#pragma unroll
    for (int j = 0; j < D_O; ++j) acc[j] += hv.z * w[j];
    w += D_O;
#pragma unroll
    for (int j = 0; j < D_O; ++j) acc[j] += hv.w * w[j];
  }
  float m = acc[0];
#pragma unroll
  for (int j = 1; j < D_O; ++j) m = fmaxf(m, acc[j]);
  float s = 0.f;
#pragma unroll
  for (int j = 0; j < D_O; ++j) {
    acc[j] = expf(acc[j] - m);
    s += acc[j];
  }
  float inv = 1.0f / s;
  float* op = out + (size_t)row * D_O;
#pragma unroll
  for (int j = 0; j < D_O; ++j) op[j] = acc[j] * inv;
}

extern "C" void kernel_launch(void* const* d_in, const int* in_sizes, int n_in,
                              void* d_out, int out_size, void* d_ws, size_t ws_size,
                              hipStream_t stream) {
  const float* x  = (const float*)d_in[0];
  const int*   ei = (const int*)d_in[1];
  const float* W1 = (const float*)d_in[2];
  const float* b1 = (const float*)d_in[3];
  const float* W2 = (const float*)d_in[4];
  const float* b2 = (const float*)d_in[5];
  const float* Wf = (const float*)d_in[6];
  const float* bf = (const float*)d_in[7];
  float* out = (float*)d_out;

  const int E = in_sizes[1] / 2;
  const int* src = ei;
  const int* dst = ei + E;

  char* ws = (char*)d_ws;
  float* g1      = (float*)(ws + OFF_G1);
  float* h1      = (float*)(ws + OFF_H1);
  int*   col     = (int*)(ws + OFF_COL);
  float* dis     = (float*)(ws + OFF_DIS);
  int*   row_ptr = (int*)(ws + OFF_ROWPTR);
  int*   cursor  = (int*)(ws + OFF_CURSOR);
  int*   deg_i   = (int*)(ws + OFF_DEGI);
  float* g2      = (float*)(ws + OFF_G1);             // g1 dead after gather1
  float* h2      = (float*)(ws + OFF_G1 + 25600000);  // after g2

  // ---- CSR build + normalization ----
  hipMemsetAsync(deg_i, 0, (size_t)NN * 4, stream);
  count_deg_kernel<<<(E + 255) / 256, 256, 0, stream>>>(dst, deg_i, E);
  make_dis_kernel<<<(NN + 255) / 256, 256, 0, stream>>>(deg_i, dis, NN);
  scan_kernel<<<1, 1024, 0, stream>>>(deg_i, row_ptr, cursor, NN);
  fill_csr_kernel<<<(E + 255) / 256, 256, 0, stream>>>(src, dst, cursor, col, E);

  // ---- layer 1 ----
  gemm_scale_kernel<D_IN, D_H1, 8>
      <<<(NN + 63) / 64, 256, 0, stream>>>(x, W1, dis, g1, NN);
  gather_kernel<D_H1, 5>
      <<<((size_t)NN * 32 + 255) / 256, 256, 0, stream>>>(g1, col, row_ptr, dis, b1, h1, NN);

  // ---- layer 2 ----
  gemm_scale_kernel<D_H1, D_H2, 4>
      <<<(NN + 63) / 64, 256, 0, stream>>>(h1, W2, dis, g2, NN);
  gather_kernel<D_H2, 4>
      <<<((size_t)NN * 16 + 255) / 256, 256, 0, stream>>>(g2, col, row_ptr, dis, b2, h2, NN);

  // ---- head + softmax ----
  final_kernel<<<(NN + 255) / 256, 256, 0, stream>>>(h2, Wf, bf, out, NN);
}

// Round 3
// 563.723 us; speedup vs baseline: 7.7363x; 1.3062x over previous
//
#include <hip/hip_runtime.h>
#include <math.h>

#define NN 100000
#define D_IN 128
#define D_H1 128
#define D_H2 64
#define D_O 10
#define SCAN_B 1024
#define NBLK ((NN + SCAN_B - 1) / SCAN_B)  // 98

// ---- workspace layout (bytes) ----
static const size_t OFF_G1     = 0;                 // N*128 f32 = 51.2 MB (later: g2 + h2)
static const size_t OFF_H1     = 51200000;          // N*128 f32 = 51.2 MB
static const size_t OFF_COL    = 102400000;         // E int32   =  6.4 MB
static const size_t OFF_DIS    = 108800000;         // N f32
static const size_t OFF_ROWPTR = 109300000;         // (N+1) int32
static const size_t OFF_CURSOR = 109800000;         // N int32
static const size_t OFF_DEGI   = 110300000;         // N int32
static const size_t OFF_INCL   = 110700000;         // N int32 (scan temp)
static const size_t OFF_BSUMS  = 111100000;         // NBLK int32
// g2 = OFF_G1 (g1 dead after gather1); h2 = OFF_G1 + 25.6MB

__global__ __launch_bounds__(256) void count_deg_kernel(
    const int* __restrict__ dst, int* __restrict__ deg, int E) {
  int i = blockIdx.x * 256 + threadIdx.x;
  if (i < E) atomicAdd(&deg[dst[i]], 1);
}

__global__ __launch_bounds__(256) void make_dis_kernel(
    const int* __restrict__ deg, float* __restrict__ dis, int n) {
  int i = blockIdx.x * 256 + threadIdx.x;
  if (i < n) dis[i] = rsqrtf((float)deg[i] + 1.0f);  // +1 = self-loop
}

// pass 1: per-block inclusive scan; write inclusive values + block sums
__global__ __launch_bounds__(SCAN_B) void scan_block_kernel(
    const int* __restrict__ deg, int* __restrict__ incl,
    int* __restrict__ bsums, int n) {
  __shared__ int sm[SCAN_B];
  const int tid = threadIdx.x;
  const int i = blockIdx.x * SCAN_B + tid;
  int v = (i < n) ? deg[i] : 0;
  sm[tid] = v;
  __syncthreads();
#pragma unroll
  for (int off = 1; off < SCAN_B; off <<= 1) {
    int t = (tid >= off) ? sm[tid - off] : 0;
    __syncthreads();
    sm[tid] += t;
    __syncthreads();
  }
  if (i < n) incl[i] = sm[tid];
  if (tid == SCAN_B - 1) bsums[blockIdx.x] = sm[tid];
}

// pass 2: every block scans the (small) block-sums array in LDS, then emits
// exclusive row_ptr + cursor. row_ptr[n] = E (sum of in-degrees) is known.
__global__ __launch_bounds__(SCAN_B) void scan_add_kernel(
    const int* __restrict__ deg, const int* __restrict__ incl,
    const int* __restrict__ bsums, int* __restrict__ row_ptr,
    int* __restrict__ cursor, int n, int E) {
  __shared__ int bs[NBLK];
  const int tid = threadIdx.x;
  if (tid < NBLK) bs[tid] = bsums[tid];
  __syncthreads();
  if (tid == 0) {
    int run = 0;
    for (int j = 0; j < NBLK; ++j) {  // serial scan of 98 values, trivial
      int t = bs[j]; bs[j] = run; run += t;
    }
  }
  __syncthreads();
  const int i = blockIdx.x * SCAN_B + tid;
  if (i < n) {
    int ex = bs[blockIdx.x] + incl[i] - deg[i];
    row_ptr[i] = ex;
    cursor[i] = ex;
  }
  if (i == n - 1) row_ptr[n] = E;
}

__global__ __launch_bounds__(256) void fill_csr_kernel(
    const int* __restrict__ src, const int* __restrict__ dst,
    int* __restrict__ cursor, int* __restrict__ col, int E) {
  int e = blockIdx.x * 256 + threadIdx.x;
  if (e < E) {
    int p = atomicAdd(&cursor[dst[e]], 1);
    col[p] = src[e];
  }
}

// C[row, :] = dis(row) * (A[row,:] @ W)   A: [nrows, K], W: [K, NOUT]
template <int K, int NOUT, int TN>
__global__ __launch_bounds__(256) void gemm_scale_kernel(
    const float* __restrict__ A, const float* __restrict__ W,
    const float* __restrict__ dis, float* __restrict__ out, int nrows) {
  constexpr int BK = 32;
  __shared__ float ws[BK * NOUT];
  __shared__ float xs[64 * 33];
  const int tid = threadIdx.x;
  const int rg = tid >> 4;
  const int cg = tid & 15;
  const int row0 = blockIdx.x * 64;

  float acc[4][TN];
#pragma unroll
  for (int r = 0; r < 4; ++r)
#pragma unroll
    for (int j = 0; j < TN; ++j) acc[r][j] = 0.f;

  for (int k0 = 0; k0 < K; k0 += BK) {
    __syncthreads();
    for (int i = tid * 4; i < BK * NOUT; i += 256 * 4) {
      *(float4*)(ws + i) = *(const float4*)(W + (size_t)k0 * NOUT + i);
    }
    for (int l = tid * 4; l < 64 * BK; l += 256 * 4) {
      int rr = l >> 5;
      int kk = l & 31;
      int row = row0 + rr;
      float4 v;
      if (row < nrows) v = *(const float4*)(A + (size_t)row * K + k0 + kk);
      else v = make_float4(0.f, 0.f, 0.f, 0.f);
      float* p = xs + rr * 33 + kk;
      p[0] = v.x; p[1] = v.y; p[2] = v.z; p[3] = v.w;
    }
    __syncthreads();
#pragma unroll
    for (int kk = 0; kk < BK; ++kk) {
      float xv[4];
#pragma unroll
      for (int r = 0; r < 4; ++r) xv[r] = xs[(rg * 4 + r) * 33 + kk];
      const float* wr = ws + kk * NOUT + cg * TN;
#pragma unroll
      for (int j4 = 0; j4 < TN; j4 += 4) {
        float4 wv = *(const float4*)(wr + j4);
#pragma unroll
        for (int r = 0; r < 4; ++r) {
          acc[r][j4 + 0] += xv[r] * wv.x;
          acc[r][j4 + 1] += xv[r] * wv.y;
          acc[r][j4 + 2] += xv[r] * wv.z;
          acc[r][j4 + 3] += xv[r] * wv.w;
        }
      }
    }
  }
#pragma unroll
  for (int r = 0; r < 4; ++r) {
    int row = row0 + rg * 4 + r;
    if (row < nrows) {
      float s = dis[row];
#pragma unroll
      for (int j4 = 0; j4 < TN; j4 += 4) {
        float4 o;
        o.x = s * acc[r][j4 + 0];
        o.y = s * acc[r][j4 + 1];
        o.z = s * acc[r][j4 + 2];
        o.w = s * acc[r][j4 + 3];
        *(float4*)(out + (size_t)row * NOUT + cg * TN + j4) = o;
      }
    }
  }
}

// h[v,:] = relu(dis[v]*(sum_{s in col[...]} g[s,:] + g[v,:]) + b)
template <int F, int LOG_LPN>
__global__ __launch_bounds__(256) void gather_kernel(
    const float* __restrict__ g, const int* __restrict__ col,
    const int* __restrict__ row_ptr, const float* __restrict__ dis,
    const float* __restrict__ b, float* __restrict__ h, int n) {
  constexpr int LPN = 1 << LOG_LPN;
  int gid = blockIdx.x * 256 + threadIdx.x;
  int v = gid >> LOG_LPN;
  if (v >= n) return;
  int c = (gid & (LPN - 1)) * 4;
  int start = row_ptr[v];
  int end = row_ptr[v + 1];
  float4 acc = *(const float4*)(g + (size_t)v * F + c);  // self-loop
  int s_next = (start < end) ? col[start] : 0;
  for (int e = start; e < end; ++e) {
    int s = s_next;
    if (e + 1 < end) s_next = col[e + 1];
    float4 t = *(const float4*)(g + (size_t)s * F + c);
    acc.x += t.x; acc.y += t.y; acc.z += t.z; acc.w += t.w;
  }
  float dv = dis[v];
  float4 bv = *(const float4*)(b + c);
  float4 r;
  r.x = fmaxf(dv * acc.x + bv.x, 0.f);
  r.y = fmaxf(dv * acc.y + bv.y, 0.f);
  r.z = fmaxf(dv * acc.z + bv.z, 0.f);
  r.w = fmaxf(dv * acc.w + bv.w, 0.f);
  *(float4*)(h + (size_t)v * F + c) = r;
}

// logits = h @ Wf + bf, softmax -> out. One thread per row.
__global__ __launch_bounds__(256) void final_kernel(
    const float* __restrict__ h, const float* __restrict__ Wf,
    const float* __restrict__ bf, float* __restrict__ out, int n) {
  __shared__ float wfs[D_H2 * D_O];
  __shared__ float bfs[D_O];
  int tid = threadIdx.x;
  for (int i = tid; i < D_H2 * D_O; i += 256) wfs[i] = Wf[i];
  if (tid < D_O) bfs[tid] = bf[tid];
  __syncthreads();
  int row = blockIdx.x * 256 + tid;
  if (row >= n) return;
  float acc[D_O];
#pragma unroll
  for (int j = 0; j < D_O; ++j) acc[j] = bfs[j];
  const float* hp = h + (size_t)row * D_H2;
  for (int k = 0; k < D_H2; k += 4) {
    float4 hv = *(const float4*)(hp + k);
    const float* w = wfs + k * D_O;
#pragma unroll
    for (int j = 0; j < D_O; ++j) acc[j] += hv.x * w[j];
    w += D_O;
#pragma unroll
    for (int j = 0; j < D_O; ++j) acc[j] += hv.y * w[j];
    w += D_O;
#pragma unroll
    for (int j = 0; j < D_O; ++j) acc[j] += hv.z * w[j];
    w += D_O;
#pragma unroll
    for (int j = 0; j < D_O; ++j) acc[j] += hv.w * w[j];
  }
  float m = acc[0];
#pragma unroll
  for (int j = 1; j < D_O; ++j) m = fmaxf(m, acc[j]);
  float s = 0.f;
#pragma unroll
  for (int j = 0; j < D_O; ++j) {
    acc[j] = expf(acc[j] - m);
    s += acc[j];
  }
  float inv = 1.0f / s;
  float* op = out + (size_t)row * D_O;
#pragma unroll
  for (int j = 0; j < D_O; ++j) op[j] = acc[j] * inv;
}

extern "C" void kernel_launch(void* const* d_in, const int* in_sizes, int n_in,
                              void* d_out, int out_size, void* d_ws, size_t ws_size,
                              hipStream_t stream) {
  const float* x  = (const float*)d_in[0];
  const int*   ei = (const int*)d_in[1];
  const float* W1 = (const float*)d_in[2];
  const float* b1 = (const float*)d_in[3];
  const float* W2 = (const float*)d_in[4];
  const float* b2 = (const float*)d_in[5];
  const float* Wf = (const float*)d_in[6];
  const float* bf = (const float*)d_in[7];
  float* out = (float*)d_out;

  const int E = in_sizes[1] / 2;
  const int* src = ei;
  const int* dst = ei + E;

  char* ws = (char*)d_ws;
  float* g1      = (float*)(ws + OFF_G1);
  float* h1      = (float*)(ws + OFF_H1);
  int*   col     = (int*)(ws + OFF_COL);
  float* dis     = (float*)(ws + OFF_DIS);
  int*   row_ptr = (int*)(ws + OFF_ROWPTR);
  int*   cursor  = (int*)(ws + OFF_CURSOR);
  int*   deg_i   = (int*)(ws + OFF_DEGI);
  int*   incl    = (int*)(ws + OFF_INCL);
  int*   bsums   = (int*)(ws + OFF_BSUMS);
  float* g2      = (float*)(ws + OFF_G1);             // g1 dead after gather1
  float* h2      = (float*)(ws + OFF_G1 + 25600000);  // after g2

  // ---- CSR build + normalization ----
  hipMemsetAsync(deg_i, 0, (size_t)NN * 4, stream);
  count_deg_kernel<<<(E + 255) / 256, 256, 0, stream>>>(dst, deg_i, E);
  make_dis_kernel<<<(NN + 255) / 256, 256, 0, stream>>>(deg_i, dis, NN);
  scan_block_kernel<<<NBLK, SCAN_B, 0, stream>>>(deg_i, incl, bsums, NN);
  scan_add_kernel<<<NBLK, SCAN_B, 0, stream>>>(deg_i, incl, bsums, row_ptr, cursor, NN, E);
  fill_csr_kernel<<<(E + 255) / 256, 256, 0, stream>>>(src, dst, cursor, col, E);

  // ---- layer 1 ----
  gemm_scale_kernel<D_IN, D_H1, 8>
      <<<(NN + 63) / 64, 256, 0, stream>>>(x, W1, dis, g1, NN);
  gather_kernel<D_H1, 5>
      <<<((size_t)NN * 32 + 255) / 256, 256, 0, stream>>>(g1, col, row_ptr, dis, b1, h1, NN);

  // ---- layer 2 ----
  gemm_scale_kernel<D_H1, D_H2, 4>
      <<<(NN + 63) / 64, 256, 0, stream>>>(h1, W2, dis, g2, NN);
  gather_kernel<D_H2, 4>
      <<<((size_t)NN * 16 + 255) / 256, 256, 0, stream>>>(g2, col, row_ptr, dis, b2, h2, NN);

  // ---- head + softmax ----
  final_kernel<<<(NN + 255) / 256, 256, 0, stream>>>(h2, Wf, bf, out, NN);
}

// Round 4
// 513.904 us; speedup vs baseline: 8.4863x; 1.0969x over previous
//
#include <hip/hip_runtime.h>
#include <math.h>

#define NN 100000
#define D_IN 128
#define D_H1 128
#define D_H2 64
#define D_O 10
#define SCAN_B 1024
#define NBLK ((NN + SCAN_B - 1) / SCAN_B)  // 98
#define RANGE_DIV 12500                    // NN/8 -> dst/12500 = XCD range id
#define EPB 2048                           // edges per block-chunk in filtered passes

// ---- workspace layout (bytes); keep <= ~111.1 MB (proven budget) ----
static const size_t OFF_G1     = 0;                 // N*128 f32 = 51.2 MB (later: g2 25.6MB)
static const size_t OFF_H1     = 51200000;          // N*128 f32 = 51.2 MB
static const size_t OFF_COL    = 102400000;         // E int32   =  6.4 MB
static const size_t OFF_DIS    = 108800000;         // N f32
static const size_t OFF_ROWPTR = 109300000;         // (N+1) int32
static const size_t OFF_CURSOR = 109800000;         // N int32
static const size_t OFF_DEGI   = 110300000;         // N int32
static const size_t OFF_INCL   = 110700000;         // N int32 (scan temp)
static const size_t OFF_BSUMS  = 111100000;         // NBLK int32

// ---- XCD-range-filtered degree count: block b&7 owns dst range [r*12500,(r+1)*12500)
// so its atomics/writes stay in one XCD's L2 and partial lines merge before eviction.
__global__ __launch_bounds__(256) void count_deg_kernel(
    const int* __restrict__ dst, int* __restrict__ deg, int E) {
  const int r = blockIdx.x & 7;
  const int base = (blockIdx.x >> 3) * EPB + threadIdx.x;
#pragma unroll
  for (int i = 0; i < EPB / 256; ++i) {
    int e = base + i * 256;
    if (e < E) {
      int d = dst[e];
      if (d / RANGE_DIV == r) atomicAdd(&deg[d], 1);
    }
  }
}

__global__ __launch_bounds__(256) void make_dis_kernel(
    const int* __restrict__ deg, float* __restrict__ dis, int n) {
  int i = blockIdx.x * 256 + threadIdx.x;
  if (i < n) dis[i] = rsqrtf((float)deg[i] + 1.0f);  // +1 = self-loop
}

// pass 1: per-block inclusive scan; write inclusive values + block sums
__global__ __launch_bounds__(SCAN_B) void scan_block_kernel(
    const int* __restrict__ deg, int* __restrict__ incl,
    int* __restrict__ bsums, int n) {
  __shared__ int sm[SCAN_B];
  const int tid = threadIdx.x;
  const int i = blockIdx.x * SCAN_B + tid;
  int v = (i < n) ? deg[i] : 0;
  sm[tid] = v;
  __syncthreads();
#pragma unroll
  for (int off = 1; off < SCAN_B; off <<= 1) {
    int t = (tid >= off) ? sm[tid - off] : 0;
    __syncthreads();
    sm[tid] += t;
    __syncthreads();
  }
  if (i < n) incl[i] = sm[tid];
  if (tid == SCAN_B - 1) bsums[blockIdx.x] = sm[tid];
}

// pass 2: each block scans the small block-sums array in LDS, emits exclusive
// row_ptr + cursor. row_ptr[n] = E (sum of in-degrees) is known.
__global__ __launch_bounds__(SCAN_B) void scan_add_kernel(
    const int* __restrict__ deg, const int* __restrict__ incl,
    const int* __restrict__ bsums, int* __restrict__ row_ptr,
    int* __restrict__ cursor, int n, int E) {
  __shared__ int bs[NBLK];
  const int tid = threadIdx.x;
  if (tid < NBLK) bs[tid] = bsums[tid];
  __syncthreads();
  if (tid == 0) {
    int run = 0;
    for (int j = 0; j < NBLK; ++j) { int t = bs[j]; bs[j] = run; run += t; }
  }
  __syncthreads();
  const int i = blockIdx.x * SCAN_B + tid;
  if (i < n) {
    int ex = bs[blockIdx.x] + incl[i] - deg[i];
    row_ptr[i] = ex;
    cursor[i] = ex;
  }
  if (i == n - 1) row_ptr[n] = E;
}

// XCD-range-filtered CSR fill: col writes for range r land in a contiguous
// ~800KB slice handled (heuristically) by one XCD -> L2 merges partial lines.
__global__ __launch_bounds__(256) void fill_csr_kernel(
    const int* __restrict__ src, const int* __restrict__ dst,
    int* __restrict__ cursor, int* __restrict__ col, int E) {
  const int r = blockIdx.x & 7;
  const int base = (blockIdx.x >> 3) * EPB + threadIdx.x;
#pragma unroll
  for (int i = 0; i < EPB / 256; ++i) {
    int e = base + i * 256;
    if (e < E) {
      int d = dst[e];
      int s = src[e];
      if (d / RANGE_DIV == r) {
        int p = atomicAdd(&cursor[d], 1);
        col[p] = s;
      }
    }
  }
}

// C[row, :] = dis(row) * (A[row,:] @ W)   A: [nrows, K], W: [K, NOUT]
template <int K, int NOUT, int TN>
__global__ __launch_bounds__(256) void gemm_scale_kernel(
    const float* __restrict__ A, const float* __restrict__ W,
    const float* __restrict__ dis, float* __restrict__ out, int nrows) {
  constexpr int BK = 32;
  __shared__ float ws[BK * NOUT];
  __shared__ float xs[64 * 33];
  const int tid = threadIdx.x;
  const int rg = tid >> 4;
  const int cg = tid & 15;
  const int row0 = blockIdx.x * 64;

  float acc[4][TN];
#pragma unroll
  for (int r = 0; r < 4; ++r)
#pragma unroll
    for (int j = 0; j < TN; ++j) acc[r][j] = 0.f;

  for (int k0 = 0; k0 < K; k0 += BK) {
    __syncthreads();
    for (int i = tid * 4; i < BK * NOUT; i += 256 * 4) {
      *(float4*)(ws + i) = *(const float4*)(W + (size_t)k0 * NOUT + i);
    }
    for (int l = tid * 4; l < 64 * BK; l += 256 * 4) {
      int rr = l >> 5;
      int kk = l & 31;
      int row = row0 + rr;
      float4 v;
      if (row < nrows) v = *(const float4*)(A + (size_t)row * K + k0 + kk);
      else v = make_float4(0.f, 0.f, 0.f, 0.f);
      float* p = xs + rr * 33 + kk;
      p[0] = v.x; p[1] = v.y; p[2] = v.z; p[3] = v.w;
    }
    __syncthreads();
#pragma unroll
    for (int kk = 0; kk < BK; ++kk) {
      float xv[4];
#pragma unroll
      for (int r = 0; r < 4; ++r) xv[r] = xs[(rg * 4 + r) * 33 + kk];
      const float* wr = ws + kk * NOUT + cg * TN;
#pragma unroll
      for (int j4 = 0; j4 < TN; j4 += 4) {
        float4 wv = *(const float4*)(wr + j4);
#pragma unroll
        for (int r = 0; r < 4; ++r) {
          acc[r][j4 + 0] += xv[r] * wv.x;
          acc[r][j4 + 1] += xv[r] * wv.y;
          acc[r][j4 + 2] += xv[r] * wv.z;
          acc[r][j4 + 3] += xv[r] * wv.w;
        }
      }
    }
  }
#pragma unroll
  for (int r = 0; r < 4; ++r) {
    int row = row0 + rg * 4 + r;
    if (row < nrows) {
      float s = dis[row];
#pragma unroll
      for (int j4 = 0; j4 < TN; j4 += 4) {
        float4 o;
        o.x = s * acc[r][j4 + 0];
        o.y = s * acc[r][j4 + 1];
        o.z = s * acc[r][j4 + 2];
        o.w = s * acc[r][j4 + 3];
        *(float4*)(out + (size_t)row * NOUT + cg * TN + j4) = o;
      }
    }
  }
}

// h[v,:] = relu(dis[v]*(sum_{s in col[...]} g[s,:] + g[v,:]) + b)
template <int F, int LOG_LPN>
__global__ __launch_bounds__(256) void gather_kernel(
    const float* __restrict__ g, const int* __restrict__ col,
    const int* __restrict__ row_ptr, const float* __restrict__ dis,
    const float* __restrict__ b, float* __restrict__ h, int n) {
  constexpr int LPN = 1 << LOG_LPN;
  int gid = blockIdx.x * 256 + threadIdx.x;
  int v = gid >> LOG_LPN;
  if (v >= n) return;
  int c = (gid & (LPN - 1)) * 4;
  int start = row_ptr[v];
  int end = row_ptr[v + 1];
  float4 acc = *(const float4*)(g + (size_t)v * F + c);  // self-loop
  int s_next = (start < end) ? col[start] : 0;
  for (int e = start; e < end; ++e) {
    int s = s_next;
    if (e + 1 < end) s_next = col[e + 1];
    float4 t = *(const float4*)(g + (size_t)s * F + c);
    acc.x += t.x; acc.y += t.y; acc.z += t.z; acc.w += t.w;
  }
  float dv = dis[v];
  float4 bv = *(const float4*)(b + c);
  float4 r;
  r.x = fmaxf(dv * acc.x + bv.x, 0.f);
  r.y = fmaxf(dv * acc.y + bv.y, 0.f);
  r.z = fmaxf(dv * acc.z + bv.z, 0.f);
  r.w = fmaxf(dv * acc.w + bv.w, 0.f);
  *(float4*)(h + (size_t)v * F + c) = r;
}

// Fused layer-2 gather + ReLU + head GEMV + softmax.
// block = 256 threads = 16 nodes x 16 lanes (F=64). h2 row lives in LDS only.
__global__ __launch_bounds__(256) void gather2_final_kernel(
    const float* __restrict__ g, const int* __restrict__ col,
    const int* __restrict__ row_ptr, const float* __restrict__ dis,
    const float* __restrict__ b2, const float* __restrict__ Wf,
    const float* __restrict__ bf, float* __restrict__ out, int n) {
  __shared__ float hs[16][68];       // 68: pad to break b128 bank aliasing
  __shared__ float wfs[D_H2 * D_O];  // 640
  __shared__ float bfs[D_O];
  __shared__ float ls[16][12];
  const int tid = threadIdx.x;
  for (int i = tid; i < D_H2 * D_O; i += 256) wfs[i] = Wf[i];
  if (tid < D_O) bfs[tid] = bf[tid];

  const int gid = blockIdx.x * 256 + tid;
  const int v = gid >> 4;
  const int nl = tid >> 4;       // node-local 0..15
  const int c = (tid & 15) * 4;  // feature chunk
  if (v < n) {
    int start = row_ptr[v];
    int end = row_ptr[v + 1];
    float4 acc = *(const float4*)(g + (size_t)v * D_H2 + c);  // self-loop
    int s_next = (start < end) ? col[start] : 0;
    for (int e = start; e < end; ++e) {
      int s = s_next;
      if (e + 1 < end) s_next = col[e + 1];
      float4 t = *(const float4*)(g + (size_t)s * D_H2 + c);
      acc.x += t.x; acc.y += t.y; acc.z += t.z; acc.w += t.w;
    }
    float dv = dis[v];
    float4 bv = *(const float4*)(b2 + c);
    hs[nl][c + 0] = fmaxf(dv * acc.x + bv.x, 0.f);
    hs[nl][c + 1] = fmaxf(dv * acc.y + bv.y, 0.f);
    hs[nl][c + 2] = fmaxf(dv * acc.z + bv.z, 0.f);
    hs[nl][c + 3] = fmaxf(dv * acc.w + bv.w, 0.f);
  }
  __syncthreads();
  // logits: one (node, class) per thread, 160 threads
  if (tid < 16 * D_O) {
    int n2 = tid / D_O;
    int j = tid % D_O;
    int v2 = blockIdx.x * 16 + n2;
    if (v2 < n) {
      float acc = bfs[j];
#pragma unroll 8
      for (int k = 0; k < D_H2; ++k) acc += hs[n2][k] * wfs[k * D_O + j];
      ls[n2][j] = acc;
    }
  }
  __syncthreads();
  // softmax per node (16 threads), probs back into ls
  if (tid < 16) {
    int v2 = blockIdx.x * 16 + tid;
    if (v2 < n) {
      float m = ls[tid][0];
#pragma unroll
      for (int j = 1; j < D_O; ++j) m = fmaxf(m, ls[tid][j]);
      float s = 0.f;
      float ex[D_O];
#pragma unroll
      for (int j = 0; j < D_O; ++j) { ex[j] = expf(ls[tid][j] - m); s += ex[j]; }
      float inv = 1.0f / s;
#pragma unroll
      for (int j = 0; j < D_O; ++j) ls[tid][j] = ex[j] * inv;
    }
  }
  __syncthreads();
  // coalesced output: 160 consecutive floats per block
  if (tid < 16 * D_O) {
    int n2 = tid / D_O;
    int j = tid % D_O;
    int idx = blockIdx.x * 16 * D_O + tid;
    if (idx < n * D_O) out[idx] = ls[n2][j];
  }
}

extern "C" void kernel_launch(void* const* d_in, const int* in_sizes, int n_in,
                              void* d_out, int out_size, void* d_ws, size_t ws_size,
                              hipStream_t stream) {
  const float* x  = (const float*)d_in[0];
  const int*   ei = (const int*)d_in[1];
  const float* W1 = (const float*)d_in[2];
  const float* b1 = (const float*)d_in[3];
  const float* W2 = (const float*)d_in[4];
  const float* b2 = (const float*)d_in[5];
  const float* Wf = (const float*)d_in[6];
  const float* bf = (const float*)d_in[7];
  float* out = (float*)d_out;

  const int E = in_sizes[1] / 2;
  const int* src = ei;
  const int* dst = ei + E;

  char* ws = (char*)d_ws;
  float* g1      = (float*)(ws + OFF_G1);
  float* h1      = (float*)(ws + OFF_H1);
  int*   col     = (int*)(ws + OFF_COL);
  float* dis     = (float*)(ws + OFF_DIS);
  int*   row_ptr = (int*)(ws + OFF_ROWPTR);
  int*   cursor  = (int*)(ws + OFF_CURSOR);
  int*   deg_i   = (int*)(ws + OFF_DEGI);
  int*   incl    = (int*)(ws + OFF_INCL);
  int*   bsums   = (int*)(ws + OFF_BSUMS);
  float* g2      = (float*)(ws + OFF_G1);  // g1 dead after gather1

  const int nchunk = (E + EPB - 1) / EPB;

  // ---- CSR build + normalization ----
  hipMemsetAsync(deg_i, 0, (size_t)NN * 4, stream);
  count_deg_kernel<<<nchunk * 8, 256, 0, stream>>>(dst, deg_i, E);
  make_dis_kernel<<<(NN + 255) / 256, 256, 0, stream>>>(deg_i, dis, NN);
  scan_block_kernel<<<NBLK, SCAN_B, 0, stream>>>(deg_i, incl, bsums, NN);
  scan_add_kernel<<<NBLK, SCAN_B, 0, stream>>>(deg_i, incl, bsums, row_ptr, cursor, NN, E);
  fill_csr_kernel<<<nchunk * 8, 256, 0, stream>>>(src, dst, cursor, col, E);

  // ---- layer 1 ----
  gemm_scale_kernel<D_IN, D_H1, 8>
      <<<(NN + 63) / 64, 256, 0, stream>>>(x, W1, dis, g1, NN);
  gather_kernel<D_H1, 5>
      <<<((size_t)NN * 32 + 255) / 256, 256, 0, stream>>>(g1, col, row_ptr, dis, b1, h1, NN);

  // ---- layer 2 ----
  gemm_scale_kernel<D_H1, D_H2, 4>
      <<<(NN + 63) / 64, 256, 0, stream>>>(h1, W2, dis, g2, NN);

  // ---- fused gather2 + head + softmax ----
  gather2_final_kernel<<<(NN + 15) / 16, 256, 0, stream>>>(
      g2, col, row_ptr, dis, b2, Wf, bf, out, NN);
}

// Round 5
// 447.055 us; speedup vs baseline: 9.7553x; 1.1495x over previous
//
#include <hip/hip_runtime.h>
#include <math.h>

#define NN 100000
#define D_IN 128
#define D_H1 128
#define D_H2 64
#define D_O 10
#define SCAN_B 1024
#define NBLK ((NN + SCAN_B - 1) / SCAN_B)  // 98
#define RANGE_DIV 12500                    // NN/8 -> dst/12500 = XCD range id
#define EPB 2048                           // edges per block-chunk in filtered passes

// ---- workspace layout (bytes) ----
// g1/h1/g2 are bf16 now (halved), offsets kept from the proven layout.
static const size_t OFF_G1     = 0;                 // N*128 bf16 = 25.6 MB (later g2: N*64 bf16)
static const size_t OFF_H1     = 51200000;          // N*128 bf16 = 25.6 MB
static const size_t OFF_COL    = 102400000;         // E int32   =  6.4 MB
static const size_t OFF_DIS    = 108800000;         // N f32
static const size_t OFF_ROWPTR = 109300000;         // (N+1) int32
static const size_t OFF_CURSOR = 109800000;         // N int32
static const size_t OFF_DEGI   = 110300000;         // N int32
static const size_t OFF_INCL   = 110700000;         // N int32 (scan temp)
static const size_t OFF_BSUMS  = 111100000;         // NBLK int32

// ---- bf16 helpers (RNE; values are finite) ----
__device__ inline unsigned int pack_bf2(float a, float b) {
  unsigned int ua = __float_as_uint(a);
  ua += 0x7fffu + ((ua >> 16) & 1u);
  unsigned int ub = __float_as_uint(b);
  ub += 0x7fffu + ((ub >> 16) & 1u);
  return (ua >> 16) | (ub & 0xffff0000u);
}
__device__ inline float bflo(unsigned int u) { return __uint_as_float(u << 16); }
__device__ inline float bfhi(unsigned int u) { return __uint_as_float(u & 0xffff0000u); }

// ---- XCD-range-filtered degree count ----
__global__ __launch_bounds__(256) void count_deg_kernel(
    const int* __restrict__ dst, int* __restrict__ deg, int E) {
  const int r = blockIdx.x & 7;
  const int base = (blockIdx.x >> 3) * EPB + threadIdx.x;
#pragma unroll
  for (int i = 0; i < EPB / 256; ++i) {
    int e = base + i * 256;
    if (e < E) {
      int d = dst[e];
      if (d / RANGE_DIV == r) atomicAdd(&deg[d], 1);
    }
  }
}

__global__ __launch_bounds__(256) void make_dis_kernel(
    const int* __restrict__ deg, float* __restrict__ dis, int n) {
  int i = blockIdx.x * 256 + threadIdx.x;
  if (i < n) dis[i] = rsqrtf((float)deg[i] + 1.0f);  // +1 = self-loop
}

__global__ __launch_bounds__(SCAN_B) void scan_block_kernel(
    const int* __restrict__ deg, int* __restrict__ incl,
    int* __restrict__ bsums, int n) {
  __shared__ int sm[SCAN_B];
  const int tid = threadIdx.x;
  const int i = blockIdx.x * SCAN_B + tid;
  int v = (i < n) ? deg[i] : 0;
  sm[tid] = v;
  __syncthreads();
#pragma unroll
  for (int off = 1; off < SCAN_B; off <<= 1) {
    int t = (tid >= off) ? sm[tid - off] : 0;
    __syncthreads();
    sm[tid] += t;
    __syncthreads();
  }
  if (i < n) incl[i] = sm[tid];
  if (tid == SCAN_B - 1) bsums[blockIdx.x] = sm[tid];
}

__global__ __launch_bounds__(SCAN_B) void scan_add_kernel(
    const int* __restrict__ deg, const int* __restrict__ incl,
    const int* __restrict__ bsums, int* __restrict__ row_ptr,
    int* __restrict__ cursor, int n, int E) {
  __shared__ int bs[NBLK];
  const int tid = threadIdx.x;
  if (tid < NBLK) bs[tid] = bsums[tid];
  __syncthreads();
  if (tid == 0) {
    int run = 0;
    for (int j = 0; j < NBLK; ++j) { int t = bs[j]; bs[j] = run; run += t; }
  }
  __syncthreads();
  const int i = blockIdx.x * SCAN_B + tid;
  if (i < n) {
    int ex = bs[blockIdx.x] + incl[i] - deg[i];
    row_ptr[i] = ex;
    cursor[i] = ex;
  }
  if (i == n - 1) row_ptr[n] = E;
}

__global__ __launch_bounds__(256) void fill_csr_kernel(
    const int* __restrict__ src, const int* __restrict__ dst,
    int* __restrict__ cursor, int* __restrict__ col, int E) {
  const int r = blockIdx.x & 7;
  const int base = (blockIdx.x >> 3) * EPB + threadIdx.x;
#pragma unroll
  for (int i = 0; i < EPB / 256; ++i) {
    int e = base + i * 256;
    if (e < E) {
      int d = dst[e];
      int s = src[e];
      if (d / RANGE_DIV == r) {
        int p = atomicAdd(&cursor[d], 1);
        col[p] = s;
      }
    }
  }
}

// C[row, :] = dis(row) * (A[row,:] @ W); A fp32 or bf16, out bf16.
// block: 256 threads, 64 rows/block, micro-tile 4 rows x TN cols.
template <int K, int NOUT, int TN, bool IN_BF>
__global__ __launch_bounds__(256) void gemm_scale_kernel(
    const void* __restrict__ A_, const float* __restrict__ W,
    const float* __restrict__ dis, unsigned short* __restrict__ out, int nrows) {
  constexpr int BK = 32;
  __shared__ float ws[BK * NOUT];
  __shared__ float xs[64 * 33];
  const int tid = threadIdx.x;
  const int rg = tid >> 4;
  const int cg = tid & 15;
  const int row0 = blockIdx.x * 64;

  float acc[4][TN];
#pragma unroll
  for (int r = 0; r < 4; ++r)
#pragma unroll
    for (int j = 0; j < TN; ++j) acc[r][j] = 0.f;

  for (int k0 = 0; k0 < K; k0 += BK) {
    __syncthreads();
    for (int i = tid * 4; i < BK * NOUT; i += 256 * 4) {
      *(float4*)(ws + i) = *(const float4*)(W + (size_t)k0 * NOUT + i);
    }
    if (IN_BF) {
      // 64x32 bf16 elems: 256 threads x 8 elems = one uint4 each
      const unsigned short* Au = (const unsigned short*)A_;
      int l = tid * 8;
      int rr = l >> 5;
      int kk = l & 31;
      int row = row0 + rr;
      float f[8];
      if (row < nrows) {
        uint4 u = *(const uint4*)(Au + (size_t)row * K + k0 + kk);
        f[0] = bflo(u.x); f[1] = bfhi(u.x);
        f[2] = bflo(u.y); f[3] = bfhi(u.y);
        f[4] = bflo(u.z); f[5] = bfhi(u.z);
        f[6] = bflo(u.w); f[7] = bfhi(u.w);
      } else {
#pragma unroll
        for (int q = 0; q < 8; ++q) f[q] = 0.f;
      }
      float* p = xs + rr * 33 + kk;
#pragma unroll
      for (int q = 0; q < 8; ++q) p[q] = f[q];
    } else {
      const float* Af = (const float*)A_;
      for (int l = tid * 4; l < 64 * BK; l += 256 * 4) {
        int rr = l >> 5;
        int kk = l & 31;
        int row = row0 + rr;
        float4 v;
        if (row < nrows) v = *(const float4*)(Af + (size_t)row * K + k0 + kk);
        else v = make_float4(0.f, 0.f, 0.f, 0.f);
        float* p = xs + rr * 33 + kk;
        p[0] = v.x; p[1] = v.y; p[2] = v.z; p[3] = v.w;
      }
    }
    __syncthreads();
#pragma unroll
    for (int kk = 0; kk < BK; ++kk) {
      float xv[4];
#pragma unroll
      for (int r = 0; r < 4; ++r) xv[r] = xs[(rg * 4 + r) * 33 + kk];
      const float* wr = ws + kk * NOUT + cg * TN;
#pragma unroll
      for (int j4 = 0; j4 < TN; j4 += 4) {
        float4 wv = *(const float4*)(wr + j4);
#pragma unroll
        for (int r = 0; r < 4; ++r) {
          acc[r][j4 + 0] += xv[r] * wv.x;
          acc[r][j4 + 1] += xv[r] * wv.y;
          acc[r][j4 + 2] += xv[r] * wv.z;
          acc[r][j4 + 3] += xv[r] * wv.w;
        }
      }
    }
  }
#pragma unroll
  for (int r = 0; r < 4; ++r) {
    int row = row0 + rg * 4 + r;
    if (row < nrows) {
      float s = dis[row];
#pragma unroll
      for (int j4 = 0; j4 < TN; j4 += 4) {
        uint2 o;
        o.x = pack_bf2(s * acc[r][j4 + 0], s * acc[r][j4 + 1]);
        o.y = pack_bf2(s * acc[r][j4 + 2], s * acc[r][j4 + 3]);
        *(uint2*)(out + (size_t)row * NOUT + cg * TN + j4) = o;
      }
    }
  }
}

// h[v,:] = relu(dis[v]*(sum g[s,:] + g[v,:]) + b), g/h bf16, fp32 accum.
// Each lane owns 8 features (one uint4 = 16B). LPN = F/8.
template <int F, int LOG_LPN>
__global__ __launch_bounds__(256) void gather_bf_kernel(
    const unsigned short* __restrict__ g, const int* __restrict__ col,
    const int* __restrict__ row_ptr, const float* __restrict__ dis,
    const float* __restrict__ b, unsigned short* __restrict__ h, int n) {
  constexpr int LPN = 1 << LOG_LPN;
  int gid = blockIdx.x * 256 + threadIdx.x;
  int v = gid >> LOG_LPN;
  if (v >= n) return;
  int c = (gid & (LPN - 1)) * 8;
  int start = row_ptr[v];
  int end = row_ptr[v + 1];
  float acc[8];
  {
    uint4 u = *(const uint4*)(g + (size_t)v * F + c);  // self-loop
    acc[0] = bflo(u.x); acc[1] = bfhi(u.x);
    acc[2] = bflo(u.y); acc[3] = bfhi(u.y);
    acc[4] = bflo(u.z); acc[5] = bfhi(u.z);
    acc[6] = bflo(u.w); acc[7] = bfhi(u.w);
  }
  int s_next = (start < end) ? col[start] : 0;
  for (int e = start; e < end; ++e) {
    int s = s_next;
    if (e + 1 < end) s_next = col[e + 1];
    uint4 u = *(const uint4*)(g + (size_t)s * F + c);
    acc[0] += bflo(u.x); acc[1] += bfhi(u.x);
    acc[2] += bflo(u.y); acc[3] += bfhi(u.y);
    acc[4] += bflo(u.z); acc[5] += bfhi(u.z);
    acc[6] += bflo(u.w); acc[7] += bfhi(u.w);
  }
  float dv = dis[v];
  float4 bv0 = *(const float4*)(b + c);
  float4 bv1 = *(const float4*)(b + c + 4);
  float r0 = fmaxf(dv * acc[0] + bv0.x, 0.f);
  float r1 = fmaxf(dv * acc[1] + bv0.y, 0.f);
  float r2 = fmaxf(dv * acc[2] + bv0.z, 0.f);
  float r3 = fmaxf(dv * acc[3] + bv0.w, 0.f);
  float r4 = fmaxf(dv * acc[4] + bv1.x, 0.f);
  float r5 = fmaxf(dv * acc[5] + bv1.y, 0.f);
  float r6 = fmaxf(dv * acc[6] + bv1.z, 0.f);
  float r7 = fmaxf(dv * acc[7] + bv1.w, 0.f);
  uint4 o;
  o.x = pack_bf2(r0, r1);
  o.y = pack_bf2(r2, r3);
  o.z = pack_bf2(r4, r5);
  o.w = pack_bf2(r6, r7);
  *(uint4*)(h + (size_t)v * F + c) = o;
}

// Fused layer-2 gather + ReLU + head GEMV + softmax. g bf16 (F=64).
// block = 256 = 32 nodes x 8 lanes (8 feats each, uint4 loads).
__global__ __launch_bounds__(256) void gather2_final_kernel(
    const unsigned short* __restrict__ g, const int* __restrict__ col,
    const int* __restrict__ row_ptr, const float* __restrict__ dis,
    const float* __restrict__ b2, const float* __restrict__ Wf,
    const float* __restrict__ bf, float* __restrict__ out, int n) {
  __shared__ float hs[32][68];
  __shared__ float wfs[D_H2 * D_O];  // 640
  __shared__ float bfs[D_O];
  __shared__ float ls[32][12];
  const int tid = threadIdx.x;
  for (int i = tid; i < D_H2 * D_O; i += 256) wfs[i] = Wf[i];
  if (tid < D_O) bfs[tid] = bf[tid];

  const int gid = blockIdx.x * 256 + tid;
  const int v = gid >> 3;
  const int nl = tid >> 3;      // node-local 0..31
  const int c = (tid & 7) * 8;  // feature chunk
  if (v < n) {
    int start = row_ptr[v];
    int end = row_ptr[v + 1];
    float acc[8];
    {
      uint4 u = *(const uint4*)(g + (size_t)v * D_H2 + c);  // self-loop
      acc[0] = bflo(u.x); acc[1] = bfhi(u.x);
      acc[2] = bflo(u.y); acc[3] = bfhi(u.y);
      acc[4] = bflo(u.z); acc[5] = bfhi(u.z);
      acc[6] = bflo(u.w); acc[7] = bfhi(u.w);
    }
    int s_next = (start < end) ? col[start] : 0;
    for (int e = start; e < end; ++e) {
      int s = s_next;
      if (e + 1 < end) s_next = col[e + 1];
      uint4 u = *(const uint4*)(g + (size_t)s * D_H2 + c);
      acc[0] += bflo(u.x); acc[1] += bfhi(u.x);
      acc[2] += bflo(u.y); acc[3] += bfhi(u.y);
      acc[4] += bflo(u.z); acc[5] += bfhi(u.z);
      acc[6] += bflo(u.w); acc[7] += bfhi(u.w);
    }
    float dv = dis[v];
    float4 bv0 = *(const float4*)(b2 + c);
    float4 bv1 = *(const float4*)(b2 + c + 4);
    hs[nl][c + 0] = fmaxf(dv * acc[0] + bv0.x, 0.f);
    hs[nl][c + 1] = fmaxf(dv * acc[1] + bv0.y, 0.f);
    hs[nl][c + 2] = fmaxf(dv * acc[2] + bv0.z, 0.f);
    hs[nl][c + 3] = fmaxf(dv * acc[3] + bv0.w, 0.f);
    hs[nl][c + 4] = fmaxf(dv * acc[4] + bv1.x, 0.f);
    hs[nl][c + 5] = fmaxf(dv * acc[5] + bv1.y, 0.f);
    hs[nl][c + 6] = fmaxf(dv * acc[6] + bv1.z, 0.f);
    hs[nl][c + 7] = fmaxf(dv * acc[7] + bv1.w, 0.f);
  }
  __syncthreads();
  // logits: (node, class) pairs, 320 over 256 threads
  for (int idx = tid; idx < 32 * D_O; idx += 256) {
    int n2 = idx / D_O;
    int j = idx % D_O;
    int v2 = blockIdx.x * 32 + n2;
    if (v2 < n) {
      float acc = bfs[j];
#pragma unroll 8
      for (int k = 0; k < D_H2; ++k) acc += hs[n2][k] * wfs[k * D_O + j];
      ls[n2][j] = acc;
    }
  }
  __syncthreads();
  // softmax per node
  if (tid < 32) {
    int v2 = blockIdx.x * 32 + tid;
    if (v2 < n) {
      float m = ls[tid][0];
#pragma unroll
      for (int j = 1; j < D_O; ++j) m = fmaxf(m, ls[tid][j]);
      float s = 0.f;
      float ex[D_O];
#pragma unroll
      for (int j = 0; j < D_O; ++j) { ex[j] = expf(ls[tid][j] - m); s += ex[j]; }
      float inv = 1.0f / s;
#pragma unroll
      for (int j = 0; j < D_O; ++j) ls[tid][j] = ex[j] * inv;
    }
  }
  __syncthreads();
  // coalesced output: 320 consecutive floats per block
  for (int idx = tid; idx < 32 * D_O; idx += 256) {
    int gidx = blockIdx.x * 32 * D_O + idx;
    if (gidx < n * D_O) out[gidx] = ls[idx / D_O][idx % D_O];
  }
}

extern "C" void kernel_launch(void* const* d_in, const int* in_sizes, int n_in,
                              void* d_out, int out_size, void* d_ws, size_t ws_size,
                              hipStream_t stream) {
  const float* x  = (const float*)d_in[0];
  const int*   ei = (const int*)d_in[1];
  const float* W1 = (const float*)d_in[2];
  const float* b1 = (const float*)d_in[3];
  const float* W2 = (const float*)d_in[4];
  const float* b2 = (const float*)d_in[5];
  const float* Wf = (const float*)d_in[6];
  const float* bf = (const float*)d_in[7];
  float* out = (float*)d_out;

  const int E = in_sizes[1] / 2;
  const int* src = ei;
  const int* dst = ei + E;

  char* ws = (char*)d_ws;
  unsigned short* g1 = (unsigned short*)(ws + OFF_G1);
  unsigned short* h1 = (unsigned short*)(ws + OFF_H1);
  int*   col     = (int*)(ws + OFF_COL);
  float* dis     = (float*)(ws + OFF_DIS);
  int*   row_ptr = (int*)(ws + OFF_ROWPTR);
  int*   cursor  = (int*)(ws + OFF_CURSOR);
  int*   deg_i   = (int*)(ws + OFF_DEGI);
  int*   incl    = (int*)(ws + OFF_INCL);
  int*   bsums   = (int*)(ws + OFF_BSUMS);
  unsigned short* g2 = (unsigned short*)(ws + OFF_G1);  // g1 dead after gather1

  const int nchunk = (E + EPB - 1) / EPB;

  // ---- CSR build + normalization ----
  hipMemsetAsync(deg_i, 0, (size_t)NN * 4, stream);
  count_deg_kernel<<<nchunk * 8, 256, 0, stream>>>(dst, deg_i, E);
  make_dis_kernel<<<(NN + 255) / 256, 256, 0, stream>>>(deg_i, dis, NN);
  scan_block_kernel<<<NBLK, SCAN_B, 0, stream>>>(deg_i, incl, bsums, NN);
  scan_add_kernel<<<NBLK, SCAN_B, 0, stream>>>(deg_i, incl, bsums, row_ptr, cursor, NN, E);
  fill_csr_kernel<<<nchunk * 8, 256, 0, stream>>>(src, dst, cursor, col, E);

  // ---- layer 1 ----
  gemm_scale_kernel<D_IN, D_H1, 8, false>
      <<<(NN + 63) / 64, 256, 0, stream>>>(x, W1, dis, g1, NN);
  gather_bf_kernel<D_H1, 4>
      <<<((size_t)NN * 16 + 255) / 256, 256, 0, stream>>>(g1, col, row_ptr, dis, b1, h1, NN);

  // ---- layer 2 ----
  gemm_scale_kernel<D_H1, D_H2, 4, true>
      <<<(NN + 63) / 64, 256, 0, stream>>>(h1, W2, dis, g2, NN);

  // ---- fused gather2 + head + softmax ----
  gather2_final_kernel<<<(NN + 31) / 32, 256, 0, stream>>>(
      g2, col, row_ptr, dis, b2, Wf, bf, out, NN);
}

// Round 6
// 369.816 us; speedup vs baseline: 11.7928x; 1.2089x over previous
//
#include <hip/hip_runtime.h>
#include <math.h>

#define NN 100000
#define D_IN 128
#define D_H1 128
#define D_H2 64
#define D_O 10
#define SCAN_B 1024
#define NBLK ((NN + SCAN_B - 1) / SCAN_B)  // 98
#define RANGE_DIV 12500                    // NN/8 -> dst/12500 = XCD range id
#define EPB 2048                           // edges per block-chunk in filtered passes

// ---- workspace layout (bytes) ----
static const size_t OFF_G1     = 0;                 // N*128 bf16 = 25.6 MB (later g2: N*64 bf16)
static const size_t OFF_H1     = 51200000;          // N*128 bf16 = 25.6 MB
static const size_t OFF_COL    = 102400000;         // E int32   =  6.4 MB
static const size_t OFF_DIS    = 108800000;         // N f32 (500KB slack after -> OOB-read safe)
static const size_t OFF_ROWPTR = 109300000;         // (N+1) int32
static const size_t OFF_CURSOR = 109800000;         // N int32
static const size_t OFF_DEGI   = 110300000;         // N int32
static const size_t OFF_INCL   = 110700000;         // N int32 (scan temp)
static const size_t OFF_BSUMS  = 111100000;         // NBLK int32

typedef __attribute__((ext_vector_type(8))) short short8;
typedef __attribute__((ext_vector_type(4))) float floatx4;

// ---- bf16 helpers (RNE; values are finite) ----
__device__ inline unsigned int pack_bf2(float a, float b) {
  unsigned int ua = __float_as_uint(a);
  ua += 0x7fffu + ((ua >> 16) & 1u);
  unsigned int ub = __float_as_uint(b);
  ub += 0x7fffu + ((ub >> 16) & 1u);
  return (ua >> 16) | (ub & 0xffff0000u);
}
__device__ inline unsigned short bf16u(float a) {
  unsigned int ua = __float_as_uint(a);
  ua += 0x7fffu + ((ua >> 16) & 1u);
  return (unsigned short)(ua >> 16);
}
__device__ inline float bflo(unsigned int u) { return __uint_as_float(u << 16); }
__device__ inline float bfhi(unsigned int u) { return __uint_as_float(u & 0xffff0000u); }
__device__ inline short8 as_short8(uint4 u) {
  union { uint4 u4; short8 s8; } c; c.u4 = u; return c.s8;
}

// ---- XCD-range-filtered degree count ----
__global__ __launch_bounds__(256) void count_deg_kernel(
    const int* __restrict__ dst, int* __restrict__ deg, int E) {
  const int r = blockIdx.x & 7;
  const int base = (blockIdx.x >> 3) * EPB + threadIdx.x;
#pragma unroll
  for (int i = 0; i < EPB / 256; ++i) {
    int e = base + i * 256;
    if (e < E) {
      int d = dst[e];
      if (d / RANGE_DIV == r) atomicAdd(&deg[d], 1);
    }
  }
}

__global__ __launch_bounds__(256) void make_dis_kernel(
    const int* __restrict__ deg, float* __restrict__ dis, int n) {
  int i = blockIdx.x * 256 + threadIdx.x;
  if (i < n) dis[i] = rsqrtf((float)deg[i] + 1.0f);  // +1 = self-loop
}

__global__ __launch_bounds__(SCAN_B) void scan_block_kernel(
    const int* __restrict__ deg, int* __restrict__ incl,
    int* __restrict__ bsums, int n) {
  __shared__ int sm[SCAN_B];
  const int tid = threadIdx.x;
  const int i = blockIdx.x * SCAN_B + tid;
  int v = (i < n) ? deg[i] : 0;
  sm[tid] = v;
  __syncthreads();
#pragma unroll
  for (int off = 1; off < SCAN_B; off <<= 1) {
    int t = (tid >= off) ? sm[tid - off] : 0;
    __syncthreads();
    sm[tid] += t;
    __syncthreads();
  }
  if (i < n) incl[i] = sm[tid];
  if (tid == SCAN_B - 1) bsums[blockIdx.x] = sm[tid];
}

__global__ __launch_bounds__(SCAN_B) void scan_add_kernel(
    const int* __restrict__ deg, const int* __restrict__ incl,
    const int* __restrict__ bsums, int* __restrict__ row_ptr,
    int* __restrict__ cursor, int n, int E) {
  __shared__ int bs[NBLK];
  const int tid = threadIdx.x;
  if (tid < NBLK) bs[tid] = bsums[tid];
  __syncthreads();
  if (tid == 0) {
    int run = 0;
    for (int j = 0; j < NBLK; ++j) { int t = bs[j]; bs[j] = run; run += t; }
  }
  __syncthreads();
  const int i = blockIdx.x * SCAN_B + tid;
  if (i < n) {
    int ex = bs[blockIdx.x] + incl[i] - deg[i];
    row_ptr[i] = ex;
    cursor[i] = ex;
  }
  if (i == n - 1) row_ptr[n] = E;
}

__global__ __launch_bounds__(256) void fill_csr_kernel(
    const int* __restrict__ src, const int* __restrict__ dst,
    int* __restrict__ cursor, int* __restrict__ col, int E) {
  const int r = blockIdx.x & 7;
  const int base = (blockIdx.x >> 3) * EPB + threadIdx.x;
#pragma unroll
  for (int i = 0; i < EPB / 256; ++i) {
    int e = base + i * 256;
    if (e < E) {
      int d = dst[e];
      int s = src[e];
      if (d / RANGE_DIV == r) {
        int p = atomicAdd(&cursor[d], 1);
        col[p] = s;
      }
    }
  }
}

// ---- MFMA GEMM: out[row,:] = bf16(dis[row] * (A[row,:] @ W)), K=128 fixed.
// A: f32 (IN_BF=false) or bf16 (true), row-major K. W: f32 [K][NOUT] -> bf16 Wt in LDS.
// Block: 4 waves x 16 rows = 64 rows. Wave computes 16 x NOUT via 16x16x32 MFMA.
// Verified layouts (guide §3/m89/m92): A-frag A[m=lane&15][k=quad*8+j];
// B-frag from Wt[n=lane&15][k=quad*8+j]; D: row(m)=quad*4+reg, col(n)=lane&15.
template <int NOUT, bool IN_BF>
__global__ __launch_bounds__(256) void gemm_mfma_kernel(
    const void* __restrict__ A_, const float* __restrict__ W,
    const float* __restrict__ dis, unsigned short* __restrict__ out, int nrows) {
  constexpr int K = 128;
  constexpr int NT = NOUT / 16;   // col-tiles per wave
  constexpr int LDW = K + 8;      // 136 bf16: 272B row stride = 16B-aligned, b128 reads conflict-free
  __shared__ unsigned short wt[NOUT * LDW];
  __shared__ unsigned short buf[4 * 16 * LDW];
  const int tid = threadIdx.x;

  // stage Wt = W^T as bf16 (one-time per block; W is L2/L3-hot)
  {
    constexpr int NGRP = 256 / NOUT;  // 2 for NOUT=128, 4 for NOUT=64
    constexpr int KG = K / NGRP;      // 64 / 32
    int n = tid % NOUT;
    int k0 = (tid / NOUT) * KG;
#pragma unroll
    for (int kb = 0; kb < KG / 8; ++kb) {
      int k = k0 + kb * 8;
      unsigned int u0 = pack_bf2(W[(size_t)(k + 0) * NOUT + n], W[(size_t)(k + 1) * NOUT + n]);
      unsigned int u1 = pack_bf2(W[(size_t)(k + 2) * NOUT + n], W[(size_t)(k + 3) * NOUT + n]);
      unsigned int u2 = pack_bf2(W[(size_t)(k + 4) * NOUT + n], W[(size_t)(k + 5) * NOUT + n]);
      unsigned int u3 = pack_bf2(W[(size_t)(k + 6) * NOUT + n], W[(size_t)(k + 7) * NOUT + n]);
      *(uint4*)(wt + n * LDW + k) = make_uint4(u0, u1, u2, u3);
    }
  }

  const int wave = tid >> 6;
  const int lane = tid & 63;
  const int quad = lane >> 4;
  const int cg = lane & 15;
  const int row0w = blockIdx.x * 64 + wave * 16;

  // A fragments for this lane's row, all 4 k-blocks (global -> regs, no LDS)
  short8 afr[4];
  {
    int row = row0w + cg;
    if (row > nrows - 1) row = nrows - 1;  // clamp: garbage rows never stored
    if (IN_BF) {
      const unsigned short* Au = (const unsigned short*)A_;
#pragma unroll
      for (int kb = 0; kb < 4; ++kb)
        afr[kb] = as_short8(*(const uint4*)(Au + (size_t)row * K + kb * 32 + quad * 8));
    } else {
      const float* Af = (const float*)A_;
#pragma unroll
      for (int kb = 0; kb < 4; ++kb) {
        const float* p = Af + (size_t)row * K + kb * 32 + quad * 8;
        float4 v0 = *(const float4*)(p);
        float4 v1 = *(const float4*)(p + 4);
        uint4 u;
        u.x = pack_bf2(v0.x, v0.y); u.y = pack_bf2(v0.z, v0.w);
        u.z = pack_bf2(v1.x, v1.y); u.w = pack_bf2(v1.z, v1.w);
        afr[kb] = as_short8(u);
      }
    }
  }
  __syncthreads();  // wt ready

  floatx4 acc[NT];
#pragma unroll
  for (int t = 0; t < NT; ++t) acc[t] = (floatx4){0.f, 0.f, 0.f, 0.f};
#pragma unroll
  for (int t = 0; t < NT; ++t) {
    const unsigned short* wrow = wt + (t * 16 + cg) * LDW;
#pragma unroll
    for (int kb = 0; kb < 4; ++kb) {
      short8 bfr = *(const short8*)(wrow + kb * 32 + quad * 8);
      acc[t] = __builtin_amdgcn_mfma_f32_16x16x32_bf16(afr[kb], bfr, acc[t], 0, 0, 0);
    }
  }

  // epilogue: dis-scale (rows quad*4..quad*4+3 -> one float4), bf16, LDS tile
  float4 dv4 = *(const float4*)(dis + row0w + quad * 4);  // OOB-safe: ws slack
  float dvs[4] = {dv4.x, dv4.y, dv4.z, dv4.w};
  unsigned short* mybuf = buf + wave * 16 * LDW;
#pragma unroll
  for (int t = 0; t < NT; ++t)
#pragma unroll
    for (int r = 0; r < 4; ++r)
      mybuf[(quad * 4 + r) * LDW + t * 16 + cg] = bf16u(acc[t][r] * dvs[r]);
  __syncthreads();  // cross-lane LDS visibility

  // coalesced writeback: uint4 per lane
  constexpr int CHUNKS = NOUT / 8;
  constexpr int RPI = 64 / CHUNKS;  // rows per instr
  int cid = lane % CHUNKS;
  int rs = lane / CHUNKS;
#pragma unroll
  for (int i = 0; i < 16 / RPI; ++i) {
    int r = rs + i * RPI;
    int grow = row0w + r;
    if (grow < nrows) {
      uint4 u = *(const uint4*)(mybuf + r * LDW + cid * 8);
      *(uint4*)(out + (size_t)grow * NOUT + cid * 8) = u;
    }
  }
}

// h[v,:] = relu(dis[v]*(sum g[s,:] + g[v,:]) + b), g/h bf16, fp32 accum.
template <int F, int LOG_LPN>
__global__ __launch_bounds__(256) void gather_bf_kernel(
    const unsigned short* __restrict__ g, const int* __restrict__ col,
    const int* __restrict__ row_ptr, const float* __restrict__ dis,
    const float* __restrict__ b, unsigned short* __restrict__ h, int n) {
  constexpr int LPN = 1 << LOG_LPN;
  int gid = blockIdx.x * 256 + threadIdx.x;
  int v = gid >> LOG_LPN;
  if (v >= n) return;
  int c = (gid & (LPN - 1)) * 8;
  int start = row_ptr[v];
  int end = row_ptr[v + 1];
  float acc[8];
  {
    uint4 u = *(const uint4*)(g + (size_t)v * F + c);  // self-loop
    acc[0] = bflo(u.x); acc[1] = bfhi(u.x);
    acc[2] = bflo(u.y); acc[3] = bfhi(u.y);
    acc[4] = bflo(u.z); acc[5] = bfhi(u.z);
    acc[6] = bflo(u.w); acc[7] = bfhi(u.w);
  }
  int s_next = (start < end) ? col[start] : 0;
  for (int e = start; e < end; ++e) {
    int s = s_next;
    if (e + 1 < end) s_next = col[e + 1];
    uint4 u = *(const uint4*)(g + (size_t)s * F + c);
    acc[0] += bflo(u.x); acc[1] += bfhi(u.x);
    acc[2] += bflo(u.y); acc[3] += bfhi(u.y);
    acc[4] += bflo(u.z); acc[5] += bfhi(u.z);
    acc[6] += bflo(u.w); acc[7] += bfhi(u.w);
  }
  float dv = dis[v];
  float4 bv0 = *(const float4*)(b + c);
  float4 bv1 = *(const float4*)(b + c + 4);
  float r0 = fmaxf(dv * acc[0] + bv0.x, 0.f);
  float r1 = fmaxf(dv * acc[1] + bv0.y, 0.f);
  float r2 = fmaxf(dv * acc[2] + bv0.z, 0.f);
  float r3 = fmaxf(dv * acc[3] + bv0.w, 0.f);
  float r4 = fmaxf(dv * acc[4] + bv1.x, 0.f);
  float r5 = fmaxf(dv * acc[5] + bv1.y, 0.f);
  float r6 = fmaxf(dv * acc[6] + bv1.z, 0.f);
  float r7 = fmaxf(dv * acc[7] + bv1.w, 0.f);
  uint4 o;
  o.x = pack_bf2(r0, r1);
  o.y = pack_bf2(r2, r3);
  o.z = pack_bf2(r4, r5);
  o.w = pack_bf2(r6, r7);
  *(uint4*)(h + (size_t)v * F + c) = o;
}

// Fused layer-2 gather + ReLU + head GEMV + softmax. g bf16 (F=64).
// block = 256 = 32 nodes x 8 lanes (8 feats each, uint4 loads).
__global__ __launch_bounds__(256) void gather2_final_kernel(
    const unsigned short* __restrict__ g, const int* __restrict__ col,
    const int* __restrict__ row_ptr, const float* __restrict__ dis,
    const float* __restrict__ b2, const float* __restrict__ Wf,
    const float* __restrict__ bf, float* __restrict__ out, int n) {
  __shared__ float hs[32][68];
  __shared__ float wfs[D_H2 * D_O];  // 640
  __shared__ float bfs[D_O];
  __shared__ float ls[32][12];
  const int tid = threadIdx.x;
  for (int i = tid; i < D_H2 * D_O; i += 256) wfs[i] = Wf[i];
  if (tid < D_O) bfs[tid] = bf[tid];

  const int gid = blockIdx.x * 256 + tid;
  const int v = gid >> 3;
  const int nl = tid >> 3;      // node-local 0..31
  const int c = (tid & 7) * 8;  // feature chunk
  if (v < n) {
    int start = row_ptr[v];
    int end = row_ptr[v + 1];
    float acc[8];
    {
      uint4 u = *(const uint4*)(g + (size_t)v * D_H2 + c);  // self-loop
      acc[0] = bflo(u.x); acc[1] = bfhi(u.x);
      acc[2] = bflo(u.y); acc[3] = bfhi(u.y);
      acc[4] = bflo(u.z); acc[5] = bfhi(u.z);
      acc[6] = bflo(u.w); acc[7] = bfhi(u.w);
    }
    int s_next = (start < end) ? col[start] : 0;
    for (int e = start; e < end; ++e) {
      int s = s_next;
      if (e + 1 < end) s_next = col[e + 1];
      uint4 u = *(const uint4*)(g + (size_t)s * D_H2 + c);
      acc[0] += bflo(u.x); acc[1] += bfhi(u.x);
      acc[2] += bflo(u.y); acc[3] += bfhi(u.y);
      acc[4] += bflo(u.z); acc[5] += bfhi(u.z);
      acc[6] += bflo(u.w); acc[7] += bfhi(u.w);
    }
    float dv = dis[v];
    float4 bv0 = *(const float4*)(b2 + c);
    float4 bv1 = *(const float4*)(b2 + c + 4);
    hs[nl][c + 0] = fmaxf(dv * acc[0] + bv0.x, 0.f);
    hs[nl][c + 1] = fmaxf(dv * acc[1] + bv0.y, 0.f);
    hs[nl][c + 2] = fmaxf(dv * acc[2] + bv0.z, 0.f);
    hs[nl][c + 3] = fmaxf(dv * acc[3] + bv0.w, 0.f);
    hs[nl][c + 4] = fmaxf(dv * acc[4] + bv1.x, 0.f);
    hs[nl][c + 5] = fmaxf(dv * acc[5] + bv1.y, 0.f);
    hs[nl][c + 6] = fmaxf(dv * acc[6] + bv1.z, 0.f);
    hs[nl][c + 7] = fmaxf(dv * acc[7] + bv1.w, 0.f);
  }
  __syncthreads();
  for (int idx = tid; idx < 32 * D_O; idx += 256) {
    int n2 = idx / D_O;
    int j = idx % D_O;
    int v2 = blockIdx.x * 32 + n2;
    if (v2 < n) {
      float acc = bfs[j];
#pragma unroll 8
      for (int k = 0; k < D_H2; ++k) acc += hs[n2][k] * wfs[k * D_O + j];
      ls[n2][j] = acc;
    }
  }
  __syncthreads();
  if (tid < 32) {
    int v2 = blockIdx.x * 32 + tid;
    if (v2 < n) {
      float m = ls[tid][0];
#pragma unroll
      for (int j = 1; j < D_O; ++j) m = fmaxf(m, ls[tid][j]);
      float s = 0.f;
      float ex[D_O];
#pragma unroll
      for (int j = 0; j < D_O; ++j) { ex[j] = expf(ls[tid][j] - m); s += ex[j]; }
      float inv = 1.0f / s;
#pragma unroll
      for (int j = 0; j < D_O; ++j) ls[tid][j] = ex[j] * inv;
    }
  }
  __syncthreads();
  for (int idx = tid; idx < 32 * D_O; idx += 256) {
    int gidx = blockIdx.x * 32 * D_O + idx;
    if (gidx < n * D_O) out[gidx] = ls[idx / D_O][idx % D_O];
  }
}

extern "C" void kernel_launch(void* const* d_in, const int* in_sizes, int n_in,
                              void* d_out, int out_size, void* d_ws, size_t ws_size,
                              hipStream_t stream) {
  const float* x  = (const float*)d_in[0];
  const int*   ei = (const int*)d_in[1];
  const float* W1 = (const float*)d_in[2];
  const float* b1 = (const float*)d_in[3];
  const float* W2 = (const float*)d_in[4];
  const float* b2 = (const float*)d_in[5];
  const float* Wf = (const float*)d_in[6];
  const float* bf = (const float*)d_in[7];
  float* out = (float*)d_out;

  const int E = in_sizes[1] / 2;
  const int* src = ei;
  const int* dst = ei + E;

  char* ws = (char*)d_ws;
  unsigned short* g1 = (unsigned short*)(ws + OFF_G1);
  unsigned short* h1 = (unsigned short*)(ws + OFF_H1);
  int*   col     = (int*)(ws + OFF_COL);
  float* dis     = (float*)(ws + OFF_DIS);
  int*   row_ptr = (int*)(ws + OFF_ROWPTR);
  int*   cursor  = (int*)(ws + OFF_CURSOR);
  int*   deg_i   = (int*)(ws + OFF_DEGI);
  int*   incl    = (int*)(ws + OFF_INCL);
  int*   bsums   = (int*)(ws + OFF_BSUMS);
  unsigned short* g2 = (unsigned short*)(ws + OFF_G1);  // g1 dead after gather1

  const int nchunk = (E + EPB - 1) / EPB;

  // ---- CSR build + normalization ----
  hipMemsetAsync(deg_i, 0, (size_t)NN * 4, stream);
  count_deg_kernel<<<nchunk * 8, 256, 0, stream>>>(dst, deg_i, E);
  make_dis_kernel<<<(NN + 255) / 256, 256, 0, stream>>>(deg_i, dis, NN);
  scan_block_kernel<<<NBLK, SCAN_B, 0, stream>>>(deg_i, incl, bsums, NN);
  scan_add_kernel<<<NBLK, SCAN_B, 0, stream>>>(deg_i, incl, bsums, row_ptr, cursor, NN, E);
  fill_csr_kernel<<<nchunk * 8, 256, 0, stream>>>(src, dst, cursor, col, E);

  // ---- layer 1 ----
  gemm_mfma_kernel<D_H1, false>
      <<<(NN + 63) / 64, 256, 0, stream>>>(x, W1, dis, g1, NN);
  gather_bf_kernel<D_H1, 4>
      <<<((size_t)NN * 16 + 255) / 256, 256, 0, stream>>>(g1, col, row_ptr, dis, b1, h1, NN);

  // ---- layer 2 ----
  gemm_mfma_kernel<D_H2, true>
      <<<(NN + 63) / 64, 256, 0, stream>>>(h1, W2, dis, g2, NN);

  // ---- fused gather2 + head + softmax ----
  gather2_final_kernel<<<(NN + 31) / 32, 256, 0, stream>>>(
      g2, col, row_ptr, dis, b2, Wf, bf, out, NN);
}